// Round 3
// baseline (18925.000 us; speedup 1.0000x reference)
//
#include <hip/hip_runtime.h>

typedef _Float16 f16;
typedef __attribute__((ext_vector_type(8))) _Float16 f16x8;
typedef __attribute__((ext_vector_type(4))) float f32x4;

#define NBATCH 1024
#define NH 1024
#define NT 336
#define NDFF 7
#define NQ 9
#define K0 1088   /* 64 (x padded) + 1024 (h0) */
#define K1 2048   /* 1024 (h0_new) + 1024 (h1) */
#define OUTSTRIDE (NT * NQ)

__device__ __forceinline__ float sigf(float x) { return 1.0f / (1.0f + __expf(-x)); }
__device__ __forceinline__ float tanhfast(float x) { return 1.0f - 2.0f / (__expf(2.0f * x) + 1.0f); }

// plain (L2-cached) staging for weights
__device__ __forceinline__ void gll_w(const void* g, void* l) {
  __builtin_amdgcn_global_load_lds((const __attribute__((address_space(1))) void*)g,
                                   (__attribute__((address_space(3))) void*)l, 16, 0, 0);
}
// agent-coherent staging for h state (SC0|SC1 = 1|16): bypasses stale per-XCD L2
__device__ __forceinline__ void gll_c(const void* g, void* l) {
  __builtin_amdgcn_global_load_lds((const __attribute__((address_space(1))) void*)g,
                                   (__attribute__((address_space(3))) void*)l, 16, 0, 17);
}

__device__ __forceinline__ void spinGE(unsigned int* c, unsigned int tgt) {
  while (__hip_atomic_load(c, __ATOMIC_RELAXED, __HIP_MEMORY_SCOPE_AGENT) < tgt) {
    __builtin_amdgcn_s_sleep(2);
  }
}

// ---------------------------------------------------------------------------
// Weight pack: rows permuted so LDS B-tile row p (0..127 within colblock cb):
//   gate = (p>>4)&3, hcol_local = (p>>6)*16 + (p&15)  -> MFMA n-index == gate.
// k pre-swizzled within each 64-col chunk: dst_k = (k&~63)|((k&63)^((p&7)<<3)).
// ---------------------------------------------------------------------------
__global__ void pack_w0(const float* __restrict__ Wih0, const float* __restrict__ Whh0,
                        f16* __restrict__ Wp0) {
  const int idx = blockIdx.x * 256 + threadIdx.x;  // exactly 4096*K0
  const int pr = idx / K0;
  const int dk = idx - pr * K0;
  const int cb = pr >> 7, p = pr & 127;
  const int gate = (p >> 4) & 3;
  const int hl = ((p >> 6) << 4) | (p & 15);
  const int j = (gate << 10) + (cb << 5) + hl;
  const int sk = (dk & ~63) | ((dk & 63) ^ ((p & 7) << 3));
  float v;
  if (sk < 8) v = Wih0[j * 8 + sk];          // col 0 = y feedback, 1..7 = features
  else if (sk < 64) v = 0.0f;                // pad
  else v = Whh0[(size_t)j * NH + (sk - 64)];
  Wp0[idx] = (f16)v;
}

__global__ void pack_w1(const float* __restrict__ Wih1, const float* __restrict__ Whh1,
                        f16* __restrict__ Wp1) {
  const int idx = blockIdx.x * 256 + threadIdx.x;  // exactly 4096*2048
  const int pr = idx >> 11;
  const int dk = idx & 2047;
  const int cb = pr >> 7, p = pr & 127;
  const int gate = (p >> 4) & 3;
  const int hl = ((p >> 6) << 4) | (p & 15);
  const int j = (gate << 10) + (cb << 5) + hl;
  const int sk = (dk & ~63) | ((dk & 63) ^ ((p & 7) << 3));
  const float v = (sk < 1024) ? Wih1[(size_t)j * NH + sk]
                              : Whh1[(size_t)j * NH + (sk - 1024)];
  Wp1[idx] = (f16)v;
}

__global__ void pack_misc(const float* __restrict__ a0, const float* __restrict__ b0,
                          const float* __restrict__ a1, const float* __restrict__ b1,
                          float* __restrict__ bias0, float* __restrict__ bias1,
                          unsigned int* __restrict__ cnt) {
  const int j = blockIdx.x * 256 + threadIdx.x;
  if (j < 4096) { bias0[j] = a0[j] + b0[j]; bias1[j] = a1[j] + b1[j]; }
  if (j < 16) cnt[j] = 0;   // aCnt[8], bCnt[8] reset every call
}

// h state stored fp16 pre-swizzled (chunk swizzle keyed by row&7).
__global__ void init_h(const float* __restrict__ h_in,
                       f16* __restrict__ h0, f16* __restrict__ h1) {
  const int idx = blockIdx.x * 256 + threadIdx.x;  // exactly 2*1024*1024
  const int l = idx >> 20;
  const int rc = idx & 1048575;
  const int row = rc >> 10;
  const int dk = idx & 1023;
  const int sk = (dk & ~63) | ((dk & 63) ^ ((row & 7) << 3));
  const float hv = h_in[((size_t)l << 20) + ((size_t)row << 10) + sk];
  if (l == 0) h0[rc] = (f16)hv;
  else        h1[rc] = (f16)hv;
}

// Sum y partials for the last timestep (t = 335).
__global__ void final_y(const float* __restrict__ ypartT, const float* __restrict__ bout,
                        float* __restrict__ dout) {
  const int idx = blockIdx.x * 256 + threadIdx.x;  // exactly 9216
  const int row = idx & 1023;
  const int q = idx >> 10;
  float s = bout[q];
#pragma unroll
  for (int nb2 = 0; nb2 < 32; ++nb2) s += ypartT[(((q << 5) + nb2) << 10) + row];
  dout[(size_t)row * OUTSTRIDE + 335 * NQ + q] = s;
}

// ---------------------------------------------------------------------------
// Persistent kernel: 256 blocks (1/CU, co-resident), each owns output tile
// (rb: 128 batch rows, cb: 32 hcols x 4 gates) for BOTH layers, all 336 steps.
// Per-rowgroup sync: aCnt[rb] (layer-0 h0 published), bCnt[rb] (layer-1
// h1+ypart published). Deferred waits keep the 3-deep LDS stage ring flowing
// across phase boundaries:
//   A_t slots: kt 1..16 (h0[t-1], ready since aCnt>=32t which B_{t-1}
//     already waited on), then kt 0 (x; needs bCnt>=32t, waited at iter 14).
//   B_t slots: kt 16..31 (h1[t-1], ready w/ bCnt>=32t), then kt 0..15
//     (h0[t]; needs aCnt>=32(t+1), waited at iter 14).
// Cross-block h/ypart traffic: agent-scope stores + SC0|SC1 staging loads
// (write-through/read-through L3) -> no cache-wide wb/inv, weights stay in L2.
// ---------------------------------------------------------------------------
__global__ __launch_bounds__(256, 1) void persist(
    const f16* __restrict__ Wp0, const f16* __restrict__ Wp1,
    const float* __restrict__ bias0, const float* __restrict__ bias1,
    f16* __restrict__ h0b0, f16* __restrict__ h0b1,
    f16* __restrict__ h1b0, f16* __restrict__ h1b1,
    unsigned int* __restrict__ cnt,
    const float* __restrict__ ff, const float* __restrict__ inpy,
    float* __restrict__ ypartT, const float* __restrict__ Wout,
    const float* __restrict__ bout, const float* __restrict__ c_in,
    float* __restrict__ dout) {
  __shared__ __align__(16) unsigned char lds8[98304 + 128 * 33 * 4];
  float* hbuf = (float*)(lds8 + 98304);

  const int tid = threadIdx.x;
  const int wv = tid >> 6;
  const int ln = tid & 63;
  const int wr = wv >> 1, wc = wv & 1;
  const int blk = blockIdx.x;
  const int rb = (blk >> 3) & 7;
  const int cb = (blk & 7) * 4 + (blk >> 6);   // XCD-striped colblocks: W L2-resident
  const int row0 = rb * 128;
  const int hcol0 = cb * 32;
  unsigned int* aCnt = cnt + rb;
  unsigned int* bCnt = cnt + 8 + rb;

  f16* h0arr[2] = {h0b0, h0b1};
  f16* h1arr[2] = {h1b0, h1b1};

  const int lanerow = ln & 15;
  const int xm = (ln & 7) << 4;
  const int kgrp = (ln >> 4) << 4;
  const int hcol = hcol0 + wc * 16 + lanerow;

  // c state lives in registers for the whole run
  float c0r[4][4], c1r[4][4];
#pragma unroll
  for (int m = 0; m < 4; ++m)
#pragma unroll
    for (int r = 0; r < 4; ++r) {
      const int row = row0 + wr * 64 + m * 16 + ((ln >> 4) << 2) + r;
      c0r[m][r] = c_in[(size_t)row * NH + hcol];
      c1r[m][r] = c_in[(size_t)(NBATCH * NH) + (size_t)row * NH + hcol];
    }

  const float b0i = bias0[hcol], b0f = bias0[NH + hcol],
              b0g = bias0[2 * NH + hcol], b0o = bias0[3 * NH + hcol];
  const float b1i = bias1[hcol], b1f = bias1[NH + hcol],
              b1g = bias1[2 * NH + hcol], b1o = bias1[3 * NH + hcol];

  auto stW = [&](const f16* W, int KDIM, int kt, int buf) {
#pragma unroll
    for (int i = 0; i < 4; ++i) {
      const int ci = wv * 4 + i;
      const int tr = ci * 8 + (ln >> 3);
      gll_w(W + (size_t)(cb * 128 + tr) * KDIM + kt * 64 + (ln & 7) * 8,
            lds8 + buf * 32768 + 16384 + ci * 1024);
    }
  };
  auto stH = [&](const f16* h, int kb, int buf) {
#pragma unroll
    for (int i = 0; i < 4; ++i) {
      const int ci = wv * 4 + i;
      const int r = ci * 8 + (ln >> 3);
      gll_c(h + (((size_t)(row0 + r)) << 10) + kb + (ln & 7) * 8,
            lds8 + buf * 32768 + ci * 1024);
    }
  };

  f32x4 acc[4][4];
  const f32x4 zf = {0.0f, 0.0f, 0.0f, 0.0f};
#pragma unroll
  for (int m = 0; m < 4; ++m)
#pragma unroll
    for (int n = 0; n < 4; ++n) acc[m][n] = zf;

  auto compute = [&](int bufc) {
    const unsigned char* Ab = lds8 + bufc * 32768;
    const unsigned char* Bb = Ab + 16384;
#pragma unroll
    for (int ks = 0; ks < 2; ++ks) {
      const int kb = (kgrp + ks * 64) ^ xm;
      f16x8 afr[4], bfr[4];
#pragma unroll
      for (int m = 0; m < 4; ++m)
        afr[m] = *(const f16x8*)(Ab + (wr * 64 + m * 16 + lanerow) * 128 + kb);
#pragma unroll
      for (int n = 0; n < 4; ++n)
        bfr[n] = *(const f16x8*)(Bb + (wc * 64 + n * 16 + lanerow) * 128 + kb);
      __builtin_amdgcn_s_setprio(1);
#pragma unroll
      for (int m = 0; m < 4; ++m)
#pragma unroll
        for (int n = 0; n < 4; ++n)
          acc[m][n] = __builtin_amdgcn_mfma_f32_16x16x32_f16(afr[m], bfr[n], acc[m][n], 0, 0, 0);
      __builtin_amdgcn_s_setprio(0);
    }
  };

  // prologue: stage A_0 slots 0,1 (kt 1,2 of layer-0 @ t=0)
  stH(h0arr[0], 0, 0);  stW(Wp0, K0, 1, 0);
  stH(h0arr[0], 64, 1); stW(Wp0, K0, 2, 1);

  int sb = 0;  // ring position (global slot index mod 3)

  for (int t = 0; t < NT; ++t) {
    const int p = t & 1;
    const f16* h0prev = h0arr[p];
    f16* h0new = h0arr[1 - p];
    const f16* h1prev = h1arr[p];
    f16* h1new = h1arr[1 - p];

    // ================= PHASE A (layer 0): 17 tiles: kt = 1..16, 0 =================
    for (int it = 0; it < 17; ++it) {
      __builtin_amdgcn_sched_barrier(0);
      if (it == 15) asm volatile("s_waitcnt vmcnt(4) lgkmcnt(0)" ::: "memory");
      else          asm volatile("s_waitcnt vmcnt(8) lgkmcnt(0)" ::: "memory");
      __builtin_amdgcn_s_barrier();
      __builtin_amdgcn_sched_barrier(0);
      const int bufc = sb;
      const int bufs = (sb + 2 >= 3) ? sb - 1 : sb + 2;

      if (it == 14) {
        // gate on B_{t-1}: ypart (x feedback + y[t-1] outputs) ready
        if (t > 0) {
          if (tid == 0) spinGE(bCnt, 32u * (unsigned)t);
          __builtin_amdgcn_s_barrier();
          __builtin_amdgcn_sched_barrier(0);
        }
        // build x-tile (A slot 16 = kt 0) into bufs A-half
        unsigned char* xb = lds8 + bufs * 32768;
        if (tid < 128) {
          const int row = row0 + tid;
          float y0;
          if (t == 0) {
            y0 = inpy[row];
          } else {
            y0 = bout[0];
#pragma unroll
            for (int nb2 = 0; nb2 < 32; ++nb2)
              y0 += __hip_atomic_load(ypartT + (nb2 << 10) + row,
                                      __ATOMIC_RELAXED, __HIP_MEMORY_SCOPE_AGENT);
          }
          const float* fsrc = ff + ((size_t)row * NT + t) * NDFF;
          f16x8 xv;
          xv[0] = (f16)y0;
#pragma unroll
          for (int jj = 0; jj < 7; ++jj) xv[1 + jj] = (f16)fsrc[jj];
          *(f16x8*)(xb + tid * 128 + ((tid & 7) << 4)) = xv;
        }
        f16x8 zv;
#pragma unroll
        for (int jj = 0; jj < 8; ++jj) zv[jj] = (f16)0.0f;
        for (int idx = tid; idx < 128 * 7; idx += 256) {
          const int r = idx / 7;
          const int ch = 1 + (idx - r * 7);
          *(f16x8*)(xb + r * 128 + ((ch ^ (r & 7)) << 4)) = zv;
        }
        // emit y[t-1] (colblocks 0..8 own one quantile each)
        if (t > 0 && cb < NQ && tid < 128) {
          const int row = row0 + tid;
          float s = bout[cb];
#pragma unroll
          for (int nb2 = 0; nb2 < 32; ++nb2)
            s += __hip_atomic_load(ypartT + (((cb << 5) + nb2) << 10) + row,
                                   __ATOMIC_RELAXED, __HIP_MEMORY_SCOPE_AGENT);
          dout[(size_t)row * OUTSTRIDE + (t - 1) * NQ + cb] = s;
        }
        stW(Wp0, K0, 0, bufs);  // B-half of x slot (4 loads -> vmcnt(4) @ it15)
      } else {
        const int s = it + 2;
        if (s <= 15)      { stH(h0prev, s * 64, bufs); stW(Wp0, K0, s + 1, bufs); }
        else if (s == 17) { stH(h1prev, 0, bufs);      stW(Wp1, K1, 16, bufs); }
        else              { stH(h1prev, 64, bufs);     stW(Wp1, K1, 17, bufs); }  // s==18
      }
      compute(bufc);
      sb = (bufc + 1 >= 3) ? 0 : bufc + 1;
    }

    // ---- A epilogue: layer-0 cell update; h0 tile -> agent stores ----
#pragma unroll
    for (int m = 0; m < 4; ++m) {
      const f32x4 vi = acc[m][0], vf = acc[m][1], vg = acc[m][2], vo = acc[m][3];
#pragma unroll
      for (int r = 0; r < 4; ++r) {
        const int rloc = wr * 64 + m * 16 + ((ln >> 4) << 2) + r;
        const int row = row0 + rloc;
        const float ig = sigf(vi[r] + b0i);
        const float fg = sigf(vf[r] + b0f);
        const float gg = tanhfast(vg[r] + b0g);
        const float og = sigf(vo[r] + b0o);
        const float cn = fg * c0r[m][r] + ig * gg;
        c0r[m][r] = cn;
        const f16 hn = (f16)(og * tanhfast(cn));
        unsigned short hb = __builtin_bit_cast(unsigned short, hn);
        unsigned short* dst = (unsigned short*)((unsigned char*)h0new + (size_t)row * 2048 +
                              ((hcol >> 6) << 7) + (((hcol & 63) << 1) ^ ((row & 7) << 4)));
        __hip_atomic_store(dst, hb, __ATOMIC_RELAXED, __HIP_MEMORY_SCOPE_AGENT);
      }
      acc[m][0] = zf; acc[m][1] = zf; acc[m][2] = zf; acc[m][3] = zf;
    }
    asm volatile("s_waitcnt vmcnt(0)" ::: "memory");  // h0 stores visible (sc-coherent)
    __syncthreads();
    if (tid == 0)
      __hip_atomic_fetch_add(aCnt, 1u, __ATOMIC_RELAXED, __HIP_MEMORY_SCOPE_AGENT);

    // ================= PHASE B (layer 1): 32 tiles: kt = 16..31, 0..15 =============
    for (int it = 0; it < 32; ++it) {
      __builtin_amdgcn_sched_barrier(0);
      asm volatile("s_waitcnt vmcnt(8) lgkmcnt(0)" ::: "memory");
      __builtin_amdgcn_s_barrier();
      __builtin_amdgcn_sched_barrier(0);
      const int bufc = sb;
      const int bufs = (sb + 2 >= 3) ? sb - 1 : sb + 2;

      if (it == 14) {  // gate h0[t] half on all group-mates' phase A
        if (tid == 0) spinGE(aCnt, 32u * (unsigned)(t + 1));
        __builtin_amdgcn_s_barrier();
        __builtin_amdgcn_sched_barrier(0);
      }
      const int s = it + 2;
      if (s <= 15)      { stH(h1prev, s * 64, bufs);       stW(Wp1, K1, 16 + s, bufs); }
      else if (s <= 31) { stH(h0new, (s - 16) * 64, bufs); stW(Wp1, K1, s - 16, bufs); }
      else              { stH(h0new, (s - 32) * 64, bufs); stW(Wp0, K0, s - 31, bufs); } // A_{t+1}
      compute(bufc);
      sb = (bufc + 1 >= 3) ? 0 : bufc + 1;
    }

    // ---- B epilogue: layer-1 cell update; h1 -> agent stores + hbuf; ypart ----
#pragma unroll
    for (int m = 0; m < 4; ++m) {
      const f32x4 vi = acc[m][0], vf = acc[m][1], vg = acc[m][2], vo = acc[m][3];
#pragma unroll
      for (int r = 0; r < 4; ++r) {
        const int rloc = wr * 64 + m * 16 + ((ln >> 4) << 2) + r;
        const int row = row0 + rloc;
        const float ig = sigf(vi[r] + b1i);
        const float fg = sigf(vf[r] + b1f);
        const float gg = tanhfast(vg[r] + b1g);
        const float og = sigf(vo[r] + b1o);
        const float cn = fg * c1r[m][r] + ig * gg;
        c1r[m][r] = cn;
        const float hnf = og * tanhfast(cn);
        const f16 hn = (f16)hnf;
        unsigned short hb = __builtin_bit_cast(unsigned short, hn);
        unsigned short* dst = (unsigned short*)((unsigned char*)h1new + (size_t)row * 2048 +
                              ((hcol >> 6) << 7) + (((hcol & 63) << 1) ^ ((row & 7) << 4)));
        __hip_atomic_store(dst, hb, __ATOMIC_RELAXED, __HIP_MEMORY_SCOPE_AGENT);
        hbuf[rloc * 33 + wc * 16 + lanerow] = hnf;
      }
      acc[m][0] = zf; acc[m][1] = zf; acc[m][2] = zf; acc[m][3] = zf;
    }
    __syncthreads();  // hbuf complete
    for (int task = tid; task < 128 * NQ; task += 256) {
      const int rloc = task & 127;
      const int q = task >> 7;
      const float* wq = Wout + q * NH + hcol0;
      float s = 0.0f;
#pragma unroll
      for (int c2 = 0; c2 < 32; ++c2) s += hbuf[rloc * 33 + c2] * wq[c2];
      __hip_atomic_store(ypartT + (size_t)((q << 5) + cb) * 1024 + row0 + rloc, s,
                         __ATOMIC_RELAXED, __HIP_MEMORY_SCOPE_AGENT);
    }
    asm volatile("s_waitcnt vmcnt(0)" ::: "memory");  // h1 + ypart stores visible
    __syncthreads();
    if (tid == 0)
      __hip_atomic_fetch_add(bCnt, 1u, __ATOMIC_RELAXED, __HIP_MEMORY_SCOPE_AGENT);
  }
}

// ---------------------------------------------------------------------------
extern "C" void kernel_launch(void* const* d_in, const int* in_sizes, int n_in,
                              void* d_out, int out_size, void* d_ws, size_t ws_size,
                              hipStream_t stream) {
  const float* inpy = (const float*)d_in[2];
  const float* h_in = (const float*)d_in[3];
  const float* c_in = (const float*)d_in[4];
  const float* ff   = (const float*)d_in[5];
  const float* Wih0 = (const float*)d_in[9];
  const float* Whh0 = (const float*)d_in[10];
  const float* bih0 = (const float*)d_in[11];
  const float* bhh0 = (const float*)d_in[12];
  const float* Wih1 = (const float*)d_in[13];
  const float* Whh1 = (const float*)d_in[14];
  const float* bih1 = (const float*)d_in[15];
  const float* bhh1 = (const float*)d_in[16];
  const float* Wout = (const float*)d_in[17];
  const float* bout = (const float*)d_in[18];
  float* dout = (float*)d_out;

  unsigned char* ws = (unsigned char*)d_ws;
  size_t off = 0;
  auto alloc = [&](size_t bytes) -> void* {
    void* p = ws + off;
    off += (bytes + 255) & ~(size_t)255;
    return p;
  };
  f16* Wp0 = (f16*)alloc((size_t)4096 * K0 * 2);
  f16* Wp1 = (f16*)alloc((size_t)4096 * K1 * 2);
  f16* h0b0 = (f16*)alloc((size_t)NBATCH * NH * 2);
  f16* h0b1 = (f16*)alloc((size_t)NBATCH * NH * 2);
  f16* h1b0 = (f16*)alloc((size_t)NBATCH * NH * 2);
  f16* h1b1 = (f16*)alloc((size_t)NBATCH * NH * 2);
  float* bias0 = (float*)alloc(4096 * 4);
  float* bias1 = (float*)alloc(4096 * 4);
  float* ypartT = (float*)alloc((size_t)NQ * 32 * 1024 * 4);
  unsigned int* cnt = (unsigned int*)alloc(64);

  pack_w0<<<(4096 * K0) / 256, 256, 0, stream>>>(Wih0, Whh0, Wp0);
  pack_w1<<<(4096 * K1) / 256, 256, 0, stream>>>(Wih1, Whh1, Wp1);
  pack_misc<<<16, 256, 0, stream>>>(bih0, bhh0, bih1, bhh1, bias0, bias1, cnt);
  init_h<<<(2 * NBATCH * NH) / 256, 256, 0, stream>>>(h_in, h0b0, h1b0);

  persist<<<256, 256, 0, stream>>>(Wp0, Wp1, bias0, bias1, h0b0, h0b1, h1b0, h1b1,
                                   cnt, ff, inpy, ypartT, Wout, bout, c_in, dout);

  final_y<<<36, 256, 0, stream>>>(ypartT, bout, dout);
}

// Round 5
// 18622.089 us; speedup vs baseline: 1.0163x; 1.0163x over previous
//
#include <hip/hip_runtime.h>

typedef _Float16 f16;
typedef __attribute__((ext_vector_type(8))) _Float16 f16x8;
typedef __attribute__((ext_vector_type(4))) float f32x4;

#define NBATCH 1024
#define NH 1024
#define NT 336
#define NDFF 7
#define NQ 9
#define K0 1088   /* 64 (x padded) + 1024 (h0) */
#define K1 2048   /* 1024 (h0_new) + 1024 (h1) */
#define OUTSTRIDE (NT * NQ)

__device__ __forceinline__ float sigf(float x) { return 1.0f / (1.0f + __expf(-x)); }
__device__ __forceinline__ float tanhfast(float x) { return 1.0f - 2.0f / (__expf(2.0f * x) + 1.0f); }

// plain (L2-cached) staging for weights
__device__ __forceinline__ void gll_w(const void* g, void* l) {
  __builtin_amdgcn_global_load_lds((const __attribute__((address_space(1))) void*)g,
                                   (__attribute__((address_space(3))) void*)l, 16, 0, 0);
}
// agent-coherent staging for h state (SC0|SC1): reads through to L3 (fresh data)
__device__ __forceinline__ void gll_c(const void* g, void* l) {
  __builtin_amdgcn_global_load_lds((const __attribute__((address_space(1))) void*)g,
                                   (__attribute__((address_space(3))) void*)l, 16, 0, 17);
}

__device__ __forceinline__ void spinGE(unsigned int* c, unsigned int tgt) {
  while (__hip_atomic_load(c, __ATOMIC_RELAXED, __HIP_MEMORY_SCOPE_AGENT) < tgt) {
    __builtin_amdgcn_s_sleep(2);
  }
}

// coherent 16B store (write-through so cross-XCD sc1 readers see it)
__device__ __forceinline__ void store16_coherent(void* p, f16x8 v) {
  asm volatile("global_store_dwordx4 %0, %1, off sc0 sc1" :: "v"(p), "v"(v) : "memory");
}

// ---------------------------------------------------------------------------
// Weight pack: rows permuted so LDS B-tile row p (0..127 within colblock cb):
//   gate = (p>>4)&3, hcol_local = (p>>6)*16 + (p&15)  -> MFMA n-index == gate.
// k pre-swizzled within each 64-col chunk: dst_k = (k&~63)|((k&63)^((p&7)<<3)).
// ---------------------------------------------------------------------------
__global__ void pack_w0(const float* __restrict__ Wih0, const float* __restrict__ Whh0,
                        f16* __restrict__ Wp0) {
  const int idx = blockIdx.x * 256 + threadIdx.x;  // exactly 4096*K0
  const int pr = idx / K0;
  const int dk = idx - pr * K0;
  const int cb = pr >> 7, p = pr & 127;
  const int gate = (p >> 4) & 3;
  const int hl = ((p >> 6) << 4) | (p & 15);
  const int j = (gate << 10) + (cb << 5) + hl;
  const int sk = (dk & ~63) | ((dk & 63) ^ ((p & 7) << 3));
  float v;
  if (sk < 8) v = Wih0[j * 8 + sk];          // col 0 = y feedback, 1..7 = features
  else if (sk < 64) v = 0.0f;                // pad
  else v = Whh0[(size_t)j * NH + (sk - 64)];
  Wp0[idx] = (f16)v;
}

__global__ void pack_w1(const float* __restrict__ Wih1, const float* __restrict__ Whh1,
                        f16* __restrict__ Wp1) {
  const int idx = blockIdx.x * 256 + threadIdx.x;  // exactly 4096*2048
  const int pr = idx >> 11;
  const int dk = idx & 2047;
  const int cb = pr >> 7, p = pr & 127;
  const int gate = (p >> 4) & 3;
  const int hl = ((p >> 6) << 4) | (p & 15);
  const int j = (gate << 10) + (cb << 5) + hl;
  const int sk = (dk & ~63) | ((dk & 63) ^ ((p & 7) << 3));
  const float v = (sk < 1024) ? Wih1[(size_t)j * NH + sk]
                              : Whh1[(size_t)j * NH + (sk - 1024)];
  Wp1[idx] = (f16)v;
}

__global__ void pack_misc(const float* __restrict__ a0, const float* __restrict__ b0,
                          const float* __restrict__ a1, const float* __restrict__ b1,
                          float* __restrict__ bias0, float* __restrict__ bias1,
                          unsigned int* __restrict__ cnt) {
  const int j = blockIdx.x * 256 + threadIdx.x;
  if (j < 4096) { bias0[j] = a0[j] + b0[j]; bias1[j] = a1[j] + b1[j]; }
  if (j < 16) cnt[j] = 0;   // aCnt[8], bCnt[8] reset every call
}

// h state stored fp16 pre-swizzled (chunk swizzle keyed by row&7).
__global__ void init_h(const float* __restrict__ h_in,
                       f16* __restrict__ h0, f16* __restrict__ h1) {
  const int idx = blockIdx.x * 256 + threadIdx.x;  // exactly 2*1024*1024
  const int l = idx >> 20;
  const int rc = idx & 1048575;
  const int row = rc >> 10;
  const int dk = idx & 1023;
  const int sk = (dk & ~63) | ((dk & 63) ^ ((row & 7) << 3));
  const float hv = h_in[((size_t)l << 20) + ((size_t)row << 10) + sk];
  if (l == 0) h0[rc] = (f16)hv;
  else        h1[rc] = (f16)hv;
}

// Sum y partials for the last timestep (t = 335).
__global__ void final_y(const float* __restrict__ ypartT, const float* __restrict__ bout,
                        float* __restrict__ dout) {
  const int idx = blockIdx.x * 256 + threadIdx.x;  // exactly 9216
  const int row = idx & 1023;
  const int q = idx >> 10;
  float s = bout[q];
#pragma unroll
  for (int nb2 = 0; nb2 < 32; ++nb2) s += ypartT[(((q << 5) + nb2) << 10) + row];
  dout[(size_t)row * OUTSTRIDE + 335 * NQ + q] = s;
}

// ---------------------------------------------------------------------------
// Persistent kernel, 4-slot LDS ring (128 KB), stage-ahead = 3 iterations.
// Slot ledger (per wave, 8 gll loads per normal iteration, in-order retire):
//   iter top: wait vmcnt(16) [= 2 newer slots in flight] -> slot(sc) landed.
//   A g13: x-slot staged with only 4 W-loads + LDS ds_writes -> waits at
//   g14/g15 are vmcnt(12); g16 back to vmcnt(16).
// Epilogues: hbuf (f32, stride 36) aliased into the just-freed slot.
// RACE FIX (round 4 -> 5): s_barrier at EPILOGUE ENTRY before writing hbuf —
// the freed slot may still be under ds_read by other waves' last compute().
// Each wave's own reads are retired before it leaves compute() (MFMA register
// deps force lgkm waits), so one barrier is sufficient.
// ---------------------------------------------------------------------------
__global__ __launch_bounds__(256, 1) void persist(
    const f16* __restrict__ Wp0, const f16* __restrict__ Wp1,
    const float* __restrict__ bias0, const float* __restrict__ bias1,
    f16* __restrict__ h0b0, f16* __restrict__ h0b1,
    f16* __restrict__ h1b0, f16* __restrict__ h1b1,
    unsigned int* __restrict__ cnt,
    const float* __restrict__ ff, const float* __restrict__ inpy,
    float* __restrict__ ypartT, const float* __restrict__ Wout,
    const float* __restrict__ bout, const float* __restrict__ c_in,
    float* __restrict__ dout) {
  __shared__ __align__(16) unsigned char lds8[131072];   // 4 x 32KB ring

  const int tid = threadIdx.x;
  const int wv = tid >> 6;
  const int ln = tid & 63;
  const int wr = wv >> 1, wc = wv & 1;
  const int blk = blockIdx.x;
  const int rb = (blk >> 3) & 7;
  const int cb = (blk & 7) * 4 + (blk >> 6);   // XCD-striped colblocks
  const int row0 = rb * 128;
  const int hcol0 = cb * 32;
  unsigned int* aCnt = cnt + rb;
  unsigned int* bCnt = cnt + 8 + rb;

  f16* h0arr[2] = {h0b0, h0b1};
  f16* h1arr[2] = {h1b0, h1b1};

  const int lanerow = ln & 15;
  const int xm = (ln & 7) << 4;
  const int kgrp = (ln >> 4) << 4;
  const int hcol = hcol0 + wc * 16 + lanerow;

  // c state lives in registers for the whole run
  float c0r[4][4], c1r[4][4];
#pragma unroll
  for (int m = 0; m < 4; ++m)
#pragma unroll
    for (int r = 0; r < 4; ++r) {
      const int row = row0 + wr * 64 + m * 16 + ((ln >> 4) << 2) + r;
      c0r[m][r] = c_in[(size_t)row * NH + hcol];
      c1r[m][r] = c_in[(size_t)(NBATCH * NH) + (size_t)row * NH + hcol];
    }

  const float b0i = bias0[hcol], b0f = bias0[NH + hcol],
              b0g = bias0[2 * NH + hcol], b0o = bias0[3 * NH + hcol];
  const float b1i = bias1[hcol], b1f = bias1[NH + hcol],
              b1g = bias1[2 * NH + hcol], b1o = bias1[3 * NH + hcol];

  auto stW = [&](const f16* W, int KDIM, int kt, int slot) {
#pragma unroll
    for (int i = 0; i < 4; ++i) {
      const int ci = wv * 4 + i;
      const int tr = ci * 8 + (ln >> 3);
      gll_w(W + (size_t)(cb * 128 + tr) * KDIM + kt * 64 + (ln & 7) * 8,
            lds8 + slot * 32768 + 16384 + ci * 1024);
    }
  };
  auto stH = [&](const f16* h, int kb, int slot) {
#pragma unroll
    for (int i = 0; i < 4; ++i) {
      const int ci = wv * 4 + i;
      const int r = ci * 8 + (ln >> 3);
      gll_c(h + (((size_t)(row0 + r)) << 10) + kb + (ln & 7) * 8,
            lds8 + slot * 32768 + ci * 1024);
    }
  };

  f32x4 acc[4][4];
  const f32x4 zf = {0.0f, 0.0f, 0.0f, 0.0f};
#pragma unroll
  for (int m = 0; m < 4; ++m)
#pragma unroll
    for (int n = 0; n < 4; ++n) acc[m][n] = zf;

  auto compute = [&](int slot) {
    const unsigned char* Ab = lds8 + slot * 32768;
    const unsigned char* Bb = Ab + 16384;
#pragma unroll
    for (int ks = 0; ks < 2; ++ks) {
      const int kb = (kgrp + ks * 64) ^ xm;
      f16x8 afr[4], bfr[4];
#pragma unroll
      for (int m = 0; m < 4; ++m)
        afr[m] = *(const f16x8*)(Ab + (wr * 64 + m * 16 + lanerow) * 128 + kb);
#pragma unroll
      for (int n = 0; n < 4; ++n)
        bfr[n] = *(const f16x8*)(Bb + (wc * 64 + n * 16 + lanerow) * 128 + kb);
      __builtin_amdgcn_s_setprio(1);
#pragma unroll
      for (int m = 0; m < 4; ++m)
#pragma unroll
        for (int n = 0; n < 4; ++n)
          acc[m][n] = __builtin_amdgcn_mfma_f32_16x16x32_f16(afr[m], bfr[n], acc[m][n], 0, 0, 0);
      __builtin_amdgcn_s_setprio(0);
    }
  };

  // epilogue helper: hbuf (in freed slot) f32 [128][36] -> fp16 swizzled 16B
  // coherent stores (2 units/thread, each unit = 8 cols of one row)
  auto h_widestore = [&](f16* hdst, float* hb) {
#pragma unroll
    for (int u2 = 0; u2 < 2; ++u2) {
      const int unit = tid * 2 + u2;          // 0..511
      const int r = unit >> 2;                // block-local row
      const int u = unit & 3;                 // 8-col group
      const f32x4 lo = *(const f32x4*)(hb + r * 36 + u * 8);
      const f32x4 hi = *(const f32x4*)(hb + r * 36 + u * 8 + 4);
      f16x8 v;
#pragma unroll
      for (int j = 0; j < 4; ++j) { v[j] = (f16)lo[j]; v[4 + j] = (f16)hi[j]; }
      const int rowg = row0 + r;
      const int pb = ((hcol0 & 63) << 1) + u * 16;   // plain byte in 128B chunk
      void* p = (unsigned char*)hdst + (size_t)rowg * 2048 + ((hcol0 >> 6) << 7) +
                (pb ^ ((rowg & 7) << 4));
      store16_coherent(p, v);
    }
  };

  // ---- prologue: stage A_0 tiles 0,1,2 into slots 0,1,2 ----
  stH(h0arr[0], 0, 0);   stW(Wp0, K0, 1, 0);
  stH(h0arr[0], 64, 1);  stW(Wp0, K0, 2, 1);
  stH(h0arr[0], 128, 2); stW(Wp0, K0, 3, 2);

  int sc = 0;  // global slot counter (slot = sc & 3)

  for (int t = 0; t < NT; ++t) {
    const int p = t & 1;
    const f16* h0prev = h0arr[p];
    f16* h0new = h0arr[1 - p];
    const f16* h1prev = h1arr[p];
    f16* h1new = h1arr[1 - p];

    // ========== PHASE A (layer 0): 17 tiles, order kt = 1..16 then 0(x) =====
#pragma unroll 1
    for (int g = 0; g < 17; ++g) {
      __builtin_amdgcn_sched_barrier(0);
      if (g == 14 || g == 15) asm volatile("s_waitcnt vmcnt(12) lgkmcnt(0)" ::: "memory");
      else                    asm volatile("s_waitcnt vmcnt(16) lgkmcnt(0)" ::: "memory");
      __builtin_amdgcn_s_barrier();
      __builtin_amdgcn_sched_barrier(0);
      const int cslot = sc & 3;
      const int tslot = (sc + 3) & 3;

      if (g == 13) {
        // gate on siblings' B_{t-1}: ypart ready (x feedback + y[t-1] out)
        if (t > 0) {
          if (tid == 0) spinGE(bCnt, 32u * (unsigned)t);
          __builtin_amdgcn_s_barrier();
          __builtin_amdgcn_sched_barrier(0);
        }
        unsigned char* xb = lds8 + tslot * 32768;
        if (tid < 128) {
          const int row = row0 + tid;
          float y0;
          if (t == 0) {
            y0 = inpy[row];
          } else {
            y0 = bout[0];
#pragma unroll
            for (int nb2 = 0; nb2 < 32; ++nb2)
              y0 += __hip_atomic_load(ypartT + (nb2 << 10) + row,
                                      __ATOMIC_RELAXED, __HIP_MEMORY_SCOPE_AGENT);
          }
          const float* fsrc = ff + ((size_t)row * NT + t) * NDFF;
          f16x8 xv;
          xv[0] = (f16)y0;
#pragma unroll
          for (int jj = 0; jj < 7; ++jj) xv[1 + jj] = (f16)fsrc[jj];
          *(f16x8*)(xb + tid * 128 + ((tid & 7) << 4)) = xv;
        }
        f16x8 zv;
#pragma unroll
        for (int jj = 0; jj < 8; ++jj) zv[jj] = (f16)0.0f;
        for (int idx = tid; idx < 128 * 7; idx += 256) {
          const int r = idx / 7;
          const int ch = 1 + (idx - r * 7);
          *(f16x8*)(xb + r * 128 + ((ch ^ (r & 7)) << 4)) = zv;
        }
        if (t > 0 && cb < NQ && tid < 128) {   // emit y[t-1]
          const int row = row0 + tid;
          float s = bout[cb];
#pragma unroll
          for (int nb2 = 0; nb2 < 32; ++nb2)
            s += __hip_atomic_load(ypartT + (((cb << 5) + nb2) << 10) + row,
                                   __ATOMIC_RELAXED, __HIP_MEMORY_SCOPE_AGENT);
          dout[(size_t)row * OUTSTRIDE + (t - 1) * NQ + cb] = s;
        }
        stW(Wp0, K0, 0, tslot);   // 4 loads only
      } else {
        const int idx = g + 3;
        if (idx <= 15)      { stH(h0prev, idx * 64, tslot); stW(Wp0, K0, idx + 1, tslot); }
        else if (idx == 17) { stH(h1prev, 0, tslot);        stW(Wp1, K1, 16, tslot); }
        else if (idx == 18) { stH(h1prev, 64, tslot);       stW(Wp1, K1, 17, tslot); }
        else                { stH(h1prev, 128, tslot);      stW(Wp1, K1, 18, tslot); }
      }
      compute(cslot);
      ++sc;
    }

    // ---- A epilogue: layer-0 cell update -> hbuf -> wide coherent stores ----
    {
      // RACE FIX: other waves may still be ds_reading the freed slot (x-slot)
      // in their last compute(); barrier before aliasing it as hbuf.
      __builtin_amdgcn_s_barrier();
      float* hb = (float*)(lds8 + ((sc - 1) & 3) * 32768);
#pragma unroll
      for (int m = 0; m < 4; ++m) {
        const f32x4 vi = acc[m][0], vf = acc[m][1], vg = acc[m][2], vo = acc[m][3];
#pragma unroll
        for (int r = 0; r < 4; ++r) {
          const int rloc = wr * 64 + m * 16 + ((ln >> 4) << 2) + r;
          const float ig = sigf(vi[r] + b0i);
          const float fg = sigf(vf[r] + b0f);
          const float gg = tanhfast(vg[r] + b0g);
          const float og = sigf(vo[r] + b0o);
          const float cn = fg * c0r[m][r] + ig * gg;
          c0r[m][r] = cn;
          hb[rloc * 36 + wc * 16 + lanerow] = og * tanhfast(cn);
        }
        acc[m][0] = zf; acc[m][1] = zf; acc[m][2] = zf; acc[m][3] = zf;
      }
      asm volatile("s_waitcnt lgkmcnt(0)" ::: "memory");
      __builtin_amdgcn_s_barrier();
      h_widestore(h0new, hb);
      asm volatile("s_waitcnt vmcnt(0)" ::: "memory");  // h0 stores visible
      __builtin_amdgcn_s_barrier();
      if (tid == 0)
        __hip_atomic_fetch_add(aCnt, 1u, __ATOMIC_RELAXED, __HIP_MEMORY_SCOPE_AGENT);
    }

    // ========== PHASE B (layer 1): 32 tiles, order = h1prev k0..15, h0new k0..15
#pragma unroll 1
    for (int b = 0; b < 32; ++b) {
      __builtin_amdgcn_sched_barrier(0);
      asm volatile("s_waitcnt vmcnt(16) lgkmcnt(0)" ::: "memory");
      __builtin_amdgcn_s_barrier();
      __builtin_amdgcn_sched_barrier(0);
      const int cslot = sc & 3;
      const int tslot = (sc + 3) & 3;

      if (b == 13) {  // gate h0new staging on all group-mates' phase A
        if (tid == 0) spinGE(aCnt, 32u * (unsigned)(t + 1));
        __builtin_amdgcn_s_barrier();
        __builtin_amdgcn_sched_barrier(0);
      }
      const int idx = b + 3;
      if (idx <= 15)      { stH(h1prev, idx * 64, tslot);        stW(Wp1, K1, 16 + idx, tslot); }
      else if (idx <= 31) { stH(h0new, (idx - 16) * 64, tslot);  stW(Wp1, K1, idx - 16, tslot); }
      else                { stH(h0new, (idx - 32) * 64, tslot);  stW(Wp0, K0, idx - 31, tslot); }
      compute(cslot);
      ++sc;
    }

    // ---- B epilogue: layer-1 cell update; h1 wide stores + ypart ----
    {
      // RACE FIX: same as A epilogue — freed slot may still be under ds_read.
      __builtin_amdgcn_s_barrier();
      float* hb = (float*)(lds8 + ((sc - 1) & 3) * 32768);
#pragma unroll
      for (int m = 0; m < 4; ++m) {
        const f32x4 vi = acc[m][0], vf = acc[m][1], vg = acc[m][2], vo = acc[m][3];
#pragma unroll
        for (int r = 0; r < 4; ++r) {
          const int rloc = wr * 64 + m * 16 + ((ln >> 4) << 2) + r;
          const float ig = sigf(vi[r] + b1i);
          const float fg = sigf(vf[r] + b1f);
          const float gg = tanhfast(vg[r] + b1g);
          const float og = sigf(vo[r] + b1o);
          const float cn = fg * c1r[m][r] + ig * gg;
          c1r[m][r] = cn;
          hb[rloc * 36 + wc * 16 + lanerow] = og * tanhfast(cn);
        }
        acc[m][0] = zf; acc[m][1] = zf; acc[m][2] = zf; acc[m][3] = zf;
      }
      asm volatile("s_waitcnt lgkmcnt(0)" ::: "memory");
      __builtin_amdgcn_s_barrier();
      h_widestore(h1new, hb);
      // y partials over this block's 32 h-cols: ypartT[q][cb][row]
      for (int task = tid; task < 128 * NQ; task += 256) {
        const int rloc = task & 127;
        const int q = task >> 7;
        const float* wq = Wout + q * NH + hcol0;
        float s = 0.0f;
#pragma unroll
        for (int c2 = 0; c2 < 32; ++c2) s += hb[rloc * 36 + c2] * wq[c2];
        __hip_atomic_store(ypartT + (size_t)((q << 5) + cb) * 1024 + row0 + rloc, s,
                           __ATOMIC_RELAXED, __HIP_MEMORY_SCOPE_AGENT);
      }
      asm volatile("s_waitcnt vmcnt(0)" ::: "memory");  // h1 + ypart visible
      __builtin_amdgcn_s_barrier();
      if (tid == 0)
        __hip_atomic_fetch_add(bCnt, 1u, __ATOMIC_RELAXED, __HIP_MEMORY_SCOPE_AGENT);
    }
  }
}

// ---------------------------------------------------------------------------
extern "C" void kernel_launch(void* const* d_in, const int* in_sizes, int n_in,
                              void* d_out, int out_size, void* d_ws, size_t ws_size,
                              hipStream_t stream) {
  const float* inpy = (const float*)d_in[2];
  const float* h_in = (const float*)d_in[3];
  const float* c_in = (const float*)d_in[4];
  const float* ff   = (const float*)d_in[5];
  const float* Wih0 = (const float*)d_in[9];
  const float* Whh0 = (const float*)d_in[10];
  const float* bih0 = (const float*)d_in[11];
  const float* bhh0 = (const float*)d_in[12];
  const float* Wih1 = (const float*)d_in[13];
  const float* Whh1 = (const float*)d_in[14];
  const float* bih1 = (const float*)d_in[15];
  const float* bhh1 = (const float*)d_in[16];
  const float* Wout = (const float*)d_in[17];
  const float* bout = (const float*)d_in[18];
  float* dout = (float*)d_out;

  unsigned char* ws = (unsigned char*)d_ws;
  size_t off = 0;
  auto alloc = [&](size_t bytes) -> void* {
    void* p = ws + off;
    off += (bytes + 255) & ~(size_t)255;
    return p;
  };
  f16* Wp0 = (f16*)alloc((size_t)4096 * K0 * 2);
  f16* Wp1 = (f16*)alloc((size_t)4096 * K1 * 2);
  f16* h0b0 = (f16*)alloc((size_t)NBATCH * NH * 2);
  f16* h0b1 = (f16*)alloc((size_t)NBATCH * NH * 2);
  f16* h1b0 = (f16*)alloc((size_t)NBATCH * NH * 2);
  f16* h1b1 = (f16*)alloc((size_t)NBATCH * NH * 2);
  float* bias0 = (float*)alloc(4096 * 4);
  float* bias1 = (float*)alloc(4096 * 4);
  float* ypartT = (float*)alloc((size_t)NQ * 32 * 1024 * 4);
  unsigned int* cnt = (unsigned int*)alloc(64);

  pack_w0<<<(4096 * K0) / 256, 256, 0, stream>>>(Wih0, Whh0, Wp0);
  pack_w1<<<(4096 * K1) / 256, 256, 0, stream>>>(Wih1, Whh1, Wp1);
  pack_misc<<<16, 256, 0, stream>>>(bih0, bhh0, bih1, bhh1, bias0, bias1, cnt);
  init_h<<<(2 * NBATCH * NH) / 256, 256, 0, stream>>>(h_in, h0b0, h1b0);

  persist<<<256, 256, 0, stream>>>(Wp0, Wp1, bias0, bias1, h0b0, h0b1, h1b0, h1b1,
                                   cnt, ff, inpy, ypartT, Wout, bout, c_in, dout);

  final_y<<<36, 256, 0, stream>>>(ypartT, bout, dout);
}